// Round 1
// baseline (29.870 us; speedup 1.0000x reference)
//
#include <hip/hip_runtime.h>
#include <math.h>

// Problem constants (match reference)
#define Bq 4
#define Nq 80
#define Mq 16
#define CHq 64
#define GAMMAq 4.0f
#define EPSq 1e-6f
#define NCOMP 46   // per-(n,a) precomputed floats per u-channel

// ---------------------------------------------------------------------------
// Kernel 1: per-(n,a) contraction of kernel weights with h_nei, plus r1 = SI(x).
// Thread t -> (na = t>>4, u = t&15). 5120 threads total.
// Output layout: pc[na][comp][u]  (u fastest, 16 wide)
//   comp 0..2   : A00[k]   = sum_v w00[u,v,k] * s[v]
//   comp 3..5   : A10[k]   = sum_v w10[u,v,k] * s[v]
//   comp 6..14  : C01[k][j]= sum_v w01[u,v,k] * V[v][j]
//   comp 15..23 : P0[k][j] = sum_v w11[0,u,v,k] * V[v][j]
//   comp 24..32 : P1[k][j] = sum_v w11[1,u,v,k] * V[v][j]
//   comp 33..41 : P2[k][j] = sum_v w11[2,u,v,k] * V[v][j]
//   comp 42     : r1_s[u]
//   comp 43..45 : r1_v[u][j]
// ---------------------------------------------------------------------------
__global__ __launch_bounds__(256) void se3_precomp(
    const float* __restrict__ h_nei,   // [B][CH][N]
    const float* __restrict__ x,       // [B][CH][N]
    const float* __restrict__ w00,     // [M][M][3]
    const float* __restrict__ w10,
    const float* __restrict__ w01,
    const float* __restrict__ w11,     // [3][M][M][3]
    const float* __restrict__ wr10,    // [M][M]
    const float* __restrict__ wr11,
    float* __restrict__ pc)
{
    int t  = blockIdx.x * blockDim.x + threadIdx.x;   // 0..5119
    int u  = t & 15;
    int na = t >> 4;                                   // 0..319
    int n  = na / Nq, a = na % Nq;

    const float* hb = h_nei + (size_t)n * CHq * Nq + a;
    float s[16];
    float V[16][3];
#pragma unroll
    for (int v = 0; v < 16; ++v) s[v] = hb[v * Nq];
#pragma unroll
    for (int v = 0; v < 16; ++v)
#pragma unroll
        for (int j = 0; j < 3; ++j) V[v][j] = hb[(16 + v * 3 + j) * Nq];

    float outc[NCOMP];

#pragma unroll
    for (int k = 0; k < 3; ++k) {
        float a00 = 0.f, a10 = 0.f;
#pragma unroll
        for (int v = 0; v < 16; ++v) {
            a00 += w00[(u * 16 + v) * 3 + k] * s[v];
            a10 += w10[(u * 16 + v) * 3 + k] * s[v];
        }
        outc[k]     = a00;
        outc[3 + k] = a10;
    }

#pragma unroll
    for (int k = 0; k < 3; ++k) {
        float c[3]  = {0.f, 0.f, 0.f};
        float p0[3] = {0.f, 0.f, 0.f};
        float p1[3] = {0.f, 0.f, 0.f};
        float p2[3] = {0.f, 0.f, 0.f};
#pragma unroll
        for (int v = 0; v < 16; ++v) {
            float w01v = w01[(u * 16 + v) * 3 + k];
            float w110 = w11[((0 * 16 + u) * 16 + v) * 3 + k];
            float w111 = w11[((1 * 16 + u) * 16 + v) * 3 + k];
            float w112 = w11[((2 * 16 + u) * 16 + v) * 3 + k];
#pragma unroll
            for (int j = 0; j < 3; ++j) {
                c[j]  += w01v * V[v][j];
                p0[j] += w110 * V[v][j];
                p1[j] += w111 * V[v][j];
                p2[j] += w112 * V[v][j];
            }
        }
#pragma unroll
        for (int j = 0; j < 3; ++j) {
            outc[6  + k * 3 + j] = c[j];
            outc[15 + k * 3 + j] = p0[j];
            outc[24 + k * 3 + j] = p1[j];
            outc[33 + k * 3 + j] = p2[j];
        }
    }

    // r1 = SelfInteraction(x) with (M,M) weights
    const float* xb = x + (size_t)n * CHq * Nq + a;
    float r1s = 0.f, r1v[3] = {0.f, 0.f, 0.f};
#pragma unroll
    for (int v = 0; v < 16; ++v) {
        r1s += wr10[u * 16 + v] * xb[v * Nq];
        float wv = wr11[u * 16 + v];
#pragma unroll
        for (int j = 0; j < 3; ++j) r1v[j] += wv * xb[(16 + v * 3 + j) * Nq];
    }
    outc[42] = r1s;
#pragma unroll
    for (int j = 0; j < 3; ++j) outc[43 + j] = r1v[j];

    float* p = pc + (size_t)na * NCOMP * 16;
#pragma unroll
    for (int c = 0; c < NCOMP; ++c) p[c * 16 + u] = outc[c];
}

// ---------------------------------------------------------------------------
// Kernel 2: one block per (n, b). 256 threads = 16 a-groups x 16 u-channels.
// Fuses: h_conv, r2, r = normact(r1+r2), gate, sum_h, sum_g, z, pre_h, new_h.
// h_conv is never materialized to global memory.
// ---------------------------------------------------------------------------
__global__ __launch_bounds__(256) void se3_main(
    const float* __restrict__ x,       // [B][CH][N]
    const float* __restrict__ hdiff,   // [B][N][N][3]
    const float* __restrict__ mask,    // [B][N][N]
    const float* __restrict__ wr20,    // [M][M]
    const float* __restrict__ wr21,
    const float* __restrict__ wz0,     // [M][2M]
    const float* __restrict__ wz1,
    const float* __restrict__ wp0,     // [M][2M]
    const float* __restrict__ wp1,
    const float* __restrict__ pc,
    float* __restrict__ out)           // [B][CH][N]
{
    const int nb    = blockIdx.x;      // 0..319
    const int n     = nb / Nq;
    const int bnode = nb % Nq;
    const int tid   = threadIdx.x;
    const int g     = tid >> 4;        // a-group 0..15
    const int u     = tid & 15;        // channel 0..15

    __shared__ float hcsh[16][65];     // per-group h_conv channels (64) + pad
    __shared__ float redH[16][68];
    __shared__ float redG[16][68];
    __shared__ float sumH[64], sumG[64];
    __shared__ float wr2s[2][256];

    wr2s[0][tid] = wr20[tid];
    wr2s[1][tid] = wr21[tid];
    __syncthreads();

    float shs = 0.f, shv0 = 0.f, shv1 = 0.f, shv2 = 0.f;
    float sgs = 0.f, sgv0 = 0.f, sgv1 = 0.f, sgv2 = 0.f;

    for (int abase = 0; abase < Nq; abase += 16) {
        const int a = abase + g;

        const float* dp = hdiff + ((size_t)(n * Nq + bnode) * Nq + a) * 3;
        const float d0 = dp[0], d1 = dp[1], d2 = dp[2];
        const float m  = mask[(size_t)(n * Nq + bnode) * Nq + a];

        const float rad = sqrtf(d0 * d0 + d1 * d1 + d2 * d2 + EPSq);
        const float inv = 1.0f / rad;
        const float nh0 = d0 * inv, nh1 = d1 * inv, nh2 = d2 * inv;
        float rb[3];
        rb[0] = expf(-GAMMAq * rad * rad);
        { float t1 = rad - 0.5f; rb[1] = expf(-GAMMAq * t1 * t1); }
        { float t2 = rad - 1.0f; rb[2] = expf(-GAMMAq * t2 * t2); }

        const float* p = pc + (size_t)(n * Nq + a) * NCOMP * 16 + u;

        float as_ = 0.f, a10 = 0.f;
        float c01[3] = {0.f, 0.f, 0.f};
        float p0[3]  = {0.f, 0.f, 0.f};
        float p1[3]  = {0.f, 0.f, 0.f};
        float p2[3]  = {0.f, 0.f, 0.f};
#pragma unroll
        for (int k = 0; k < 3; ++k) {
            const float r = rb[k];
            as_ += r * p[(0 + k) * 16];
            a10 += r * p[(3 + k) * 16];
#pragma unroll
            for (int j = 0; j < 3; ++j) {
                c01[j] += r * p[(6  + k * 3 + j) * 16];
                p0[j]  += r * p[(15 + k * 3 + j) * 16];
                p1[j]  += r * p[(24 + k * 3 + j) * 16];
                p2[j]  += r * p[(33 + k * 3 + j) * 16];
            }
        }

        const float hcs = m * (as_ + c01[0] * nh0 + c01[1] * nh1 + c01[2] * nh2);
        const float cr0 = p1[1] * nh2 - p1[2] * nh1;
        const float cr1 = p1[2] * nh0 - p1[0] * nh2;
        const float cr2 = p1[0] * nh1 - p1[1] * nh0;
        const float pd  = p2[0] * nh0 + p2[1] * nh1 + p2[2] * nh2;
        const float third = 1.0f / 3.0f;
        const float hv0 = m * (nh0 * a10 + p0[0] + cr0 + nh0 * pd - p2[0] * third);
        const float hv1 = m * (nh1 * a10 + p0[1] + cr1 + nh1 * pd - p2[1] * third);
        const float hv2 = m * (nh2 * a10 + p0[2] + cr2 + nh2 * pd - p2[2] * third);

        hcsh[g][u]              = hcs;
        hcsh[g][16 + u * 3 + 0] = hv0;
        hcsh[g][16 + u * 3 + 1] = hv1;
        hcsh[g][16 + u * 3 + 2] = hv2;
        __syncthreads();

        // r2 = SI(h_conv) for this pair
        float r2s = 0.f, r2v0 = 0.f, r2v1 = 0.f, r2v2 = 0.f;
#pragma unroll
        for (int v = 0; v < 16; ++v) {
            r2s += wr2s[0][u * 16 + v] * hcsh[g][v];
            const float w = wr2s[1][u * 16 + v];
            r2v0 += w * hcsh[g][16 + v * 3 + 0];
            r2v1 += w * hcsh[g][16 + v * 3 + 1];
            r2v2 += w * hcsh[g][16 + v * 3 + 2];
        }

        // r = norm_act(r1 + r2, sigmoid); gate factor
        const float r1s  = p[42 * 16];
        const float r1v0 = p[43 * 16], r1v1 = p[44 * 16], r1v2 = p[45 * 16];
        const float rs   = 1.0f / (1.0f + expf(-(r1s + r2s)));
        const float wv0 = r1v0 + r2v0, wv1 = r1v1 + r2v1, wv2 = r1v2 + r2v2;
        const float nn  = sqrtf(wv0 * wv0 + wv1 * wv1 + wv2 * wv2 + EPSq);
        const float sc  = (1.0f / (1.0f + expf(-nn))) / nn;
        const float rv0 = wv0 * sc, rv1 = wv1 * sc, rv2 = wv2 * sc;
        const float fs  = fabsf(rs);
        const float fv  = sqrtf(rv0 * rv0 + rv1 * rv1 + rv2 * rv2 + EPSq);

        shs += hcs;        shv0 += hv0;      shv1 += hv1;      shv2 += hv2;
        sgs += fs * hcs;   sgv0 += fv * hv0; sgv1 += fv * hv1; sgv2 += fv * hv2;
        __syncthreads();   // protect hcsh before next iteration's write
    }

    // reduce partial sums over the 16 a-groups
    redH[g][u]              = shs;
    redH[g][16 + u * 3 + 0] = shv0;
    redH[g][16 + u * 3 + 1] = shv1;
    redH[g][16 + u * 3 + 2] = shv2;
    redG[g][u]              = sgs;
    redG[g][16 + u * 3 + 0] = sgv0;
    redG[g][16 + u * 3 + 1] = sgv1;
    redG[g][16 + u * 3 + 2] = sgv2;
    __syncthreads();

    if (tid < 64) {
        float sh = 0.f, sg = 0.f;
#pragma unroll
        for (int gg = 0; gg < 16; ++gg) { sh += redH[gg][tid]; sg += redG[gg][tid]; }
        sumH[tid] = sh;
        sumG[tid] = sg;
    }
    __syncthreads();

    // final per-(n,b) channel math: z, pre_h, new_h   (16 active threads)
    if (tid < 16) {
        const float* xb = x + (size_t)n * CHq * Nq + bnode;

        float zs_in = 0.f, ps_in = 0.f;
        float zv[3] = {0.f, 0.f, 0.f};
        float pv[3] = {0.f, 0.f, 0.f};
#pragma unroll
        for (int mm = 0; mm < 32; ++mm) {
            float Sh, Sg;
            if (mm < 16) { const float xv = xb[mm * Nq]; Sh = xv; Sg = xv; }
            else         { Sh = sumH[mm - 16]; Sg = sumG[mm - 16]; }
            zs_in += wz0[tid * 32 + mm] * Sh;
            ps_in += wp0[tid * 32 + mm] * Sg;
            const float wz = wz1[tid * 32 + mm];
            const float wp = wp1[tid * 32 + mm];
#pragma unroll
            for (int j = 0; j < 3; ++j) {
                float Vh, Vg;
                if (mm < 16) { const float xv = xb[(16 + mm * 3 + j) * Nq]; Vh = xv; Vg = xv; }
                else { Vh = sumH[16 + (mm - 16) * 3 + j]; Vg = sumG[16 + (mm - 16) * 3 + j]; }
                zv[j] += wz * Vh;
                pv[j] += wp * Vg;
            }
        }

        // z = norm_act(., sigmoid)
        const float zs  = 1.0f / (1.0f + expf(-zs_in));
        const float zn  = sqrtf(zv[0] * zv[0] + zv[1] * zv[1] + zv[2] * zv[2] + EPSq);
        const float zsc = (1.0f / (1.0f + expf(-zn))) / zn;
        const float zv0 = zv[0] * zsc, zv1 = zv[1] * zsc, zv2 = zv[2] * zsc;
        // pre_h = norm_act(., tanh)
        const float phs = tanhf(ps_in);
        const float pn  = sqrtf(pv[0] * pv[0] + pv[1] * pv[1] + pv[2] * pv[2] + EPSq);
        const float psc = tanhf(pn) / pn;
        const float pv0 = pv[0] * psc, pv1 = pv[1] * psc, pv2 = pv[2] * psc;
        // gate factors from z
        const float gfs = fabsf(zs);
        const float gfv = sqrtf(zv0 * zv0 + zv1 * zv1 + zv2 * zv2 + EPSq);

        float* ob = out + (size_t)n * CHq * Nq + bnode;
        const float sh_s = sumH[tid];
        ob[tid * Nq] = sh_s + gfs * (phs + sh_s);
        const float shv_0 = sumH[16 + tid * 3 + 0];
        const float shv_1 = sumH[16 + tid * 3 + 1];
        const float shv_2 = sumH[16 + tid * 3 + 2];
        ob[(16 + tid * 3 + 0) * Nq] = shv_0 + gfv * (pv0 + shv_0);
        ob[(16 + tid * 3 + 1) * Nq] = shv_1 + gfv * (pv1 + shv_1);
        ob[(16 + tid * 3 + 2) * Nq] = shv_2 + gfv * (pv2 + shv_2);
    }
}

// ---------------------------------------------------------------------------
extern "C" void kernel_launch(void* const* d_in, const int* in_sizes, int n_in,
                              void* d_out, int out_size, void* d_ws, size_t ws_size,
                              hipStream_t stream) {
    const float* x      = (const float*)d_in[0];
    const float* h_nei  = (const float*)d_in[1];
    const float* hdiff  = (const float*)d_in[2];
    const float* mask   = (const float*)d_in[3];
    const float* w00    = (const float*)d_in[4];
    const float* w10    = (const float*)d_in[5];
    const float* w01    = (const float*)d_in[6];
    const float* w11    = (const float*)d_in[7];
    const float* wz0    = (const float*)d_in[8];
    const float* wz1    = (const float*)d_in[9];
    const float* wr10   = (const float*)d_in[10];
    const float* wr11   = (const float*)d_in[11];
    const float* wr20   = (const float*)d_in[12];
    const float* wr21   = (const float*)d_in[13];
    const float* wp0    = (const float*)d_in[14];
    const float* wp1    = (const float*)d_in[15];
    float* out = (float*)d_out;
    float* pc  = (float*)d_ws;   // needs B*N*NCOMP*16*4 = 942,080 bytes

    se3_precomp<<<(Bq * Nq * 16 + 255) / 256, 256, 0, stream>>>(
        h_nei, x, w00, w10, w01, w11, wr10, wr11, pc);
    se3_main<<<Bq * Nq, 256, 0, stream>>>(
        x, hdiff, mask, wr20, wr21, wz0, wz1, wp0, wp1, pc, out);
}